// Round 18
// baseline (727.875 us; speedup 1.0000x reference)
//
#include <hip/hip_runtime.h>

#define NN 10000
#define NE 160000
#define NG 64
#define NT 5
#define NF 75
#define NL 4
#define LOG17 2.8332133f  /* log(17.0) */
#define ROWP 400          /* out1b/baseb padded row: 5 towers x 80 */
#define A1STR 104         /* k_gemm1 LDS A row stride */
#define NCT 56            /* WgS col-tiles (843 used, padded to 56*16=896) */
#define TOTW45 (NL*NT*3*2*16*320)   /* 614,400 */
#define TOTWG  (NL*NCT*2*16*96)     /* 688,128 — grid covers max of both */

typedef __attribute__((ext_vector_type(8))) short short8v;
typedef __attribute__((ext_vector_type(4))) float float4v;

__device__ __forceinline__ unsigned short f2bf(float x){
  unsigned u = __float_as_uint(x);
  unsigned r = (u + 0x7FFFu + ((u >> 16) & 1u)) >> 16;
  return (unsigned short)r;
}
__device__ __forceinline__ float blo(unsigned u){ return __uint_as_float(u << 16); }
__device__ __forceinline__ float bhi(unsigned u){ return __uint_as_float(u & 0xFFFF0000u); }

// MFMA 16x16x32 bf16 fragment k-order: pos = ks*32 + b*8 + half*4 + j
__device__ __forceinline__ int swzk(int k){
  int ks = k >> 5, r = k & 31;
  return (ks << 5) | (((r & 15) >> 2) << 3) | ((r >> 4) << 2) | (r & 3);
}
__device__ __forceinline__ short8v ld8(const unsigned short* p){
  union { uint4 u; short8v v; } x;
  x.u = *(const uint4*)p;
  return x.v;
}

// ------------- setup: h init + zero cnt/bnS/pooled
__global__ __launch_bounds__(256) void k_init(const float* __restrict__ x,
    const float* __restrict__ W, const float* __restrict__ b, float* __restrict__ h,
    int* __restrict__ cnt, float* __restrict__ bnS, float* __restrict__ pooled){
  int i = blockIdx.x*256 + threadIdx.x;
  if (i < NN) cnt[i] = 0;
  if (i < NL*160) bnS[i] = 0.f;
  if (i < NG*75) pooled[i] = 0.f;
  if (i >= NN*NF) return;
  int n = i / NF, f = i - n*NF;
  h[i] = x[2*n]*W[f] + x[2*n+1]*W[NF+f] + b[f];
}

__global__ __launch_bounds__(256) void k_count(const int* __restrict__ ei, int* __restrict__ cnt){
  int e = blockIdx.x*256 + threadIdx.x;
  if (e < NE) atomicAdd(&cnt[ei[NE + e]], 1);   // row 1 = dst
}

// 1-block scan, thread owns 10 contiguous nodes.
__global__ __launch_bounds__(1024) void k_scan(const int* __restrict__ cnt,
    int* __restrict__ off, int* __restrict__ cur){
  __shared__ int buf[1024];
  int tid = threadIdx.x;
  int base = tid*10;
  int loc[10];
  int s = 0;
  #pragma unroll
  for (int j = 0; j < 10; ++j){
    int i = base + j;
    loc[j] = s;
    s += (i < NN) ? cnt[i] : 0;
  }
  buf[tid] = s;
  __syncthreads();
  for (int d = 1; d < 1024; d <<= 1){
    int t = (tid >= d) ? buf[tid - d] : 0;
    __syncthreads();
    buf[tid] += t;
    __syncthreads();
  }
  int ex = buf[tid] - s;
  #pragma unroll
  for (int j = 0; j < 10; ++j){
    int i = base + j;
    if (i < NN){ int v = ex + loc[j]; off[i] = v; cur[i] = v; }
  }
  if (tid == 1023) off[NN] = ex + s;
}

__global__ __launch_bounds__(256) void k_scatter(const int* __restrict__ ei,
    int* __restrict__ cur, int* __restrict__ csr){
  int e = blockIdx.x*256 + threadIdx.x;
  if (e < NE){
    int d = ei[NE + e];
    int p = atomicAdd(&cur[d], 1);
    csr[p] = ei[e];   // src node
  }
}

// merged weight build: grid covers max(TOTW45, TOTWG) = TOTWG.
__global__ __launch_bounds__(256) void k_build(const float* __restrict__ preW,
    const float* __restrict__ postW, unsigned short* __restrict__ W45S,
    unsigned short* __restrict__ WgS){
  int idx = blockIdx.x*256 + threadIdx.x;
  if (idx < TOTW45){
    int kpos = idx % 320;
    int rem = idx / 320;
    int n = rem & 15; rem >>= 4;
    int p = rem & 1;  rem >>= 1;
    int g = rem % 3;  rem /= 3;
    int t = rem % 5;
    int l = rem / 5;
    int ks = kpos >> 5, r = kpos & 31;
    int b = (r >> 3) & 3, half = (r >> 2) & 1, j = r & 3;
    int kp = ks*32 + half*16 + b*4 + j;
    int stat = kp / 80, u = kp - stat*80;
    float val = 0.f;
    if (n < 15 && u < 75)
      val = postW[((size_t)(l*NT + t)*975 + 75 + g*300 + stat*75 + u)*15 + n];
    unsigned short hi = f2bf(val);
    unsigned short outv = hi;
    if (p){
      float rsd = val - __uint_as_float(((unsigned)hi) << 16);
      outv = f2bf(rsd);
    }
    W45S[idx] = outv;
  }
  if (idx < TOTWG){
    int kpos = idx % 96;
    int rem = idx / 96;
    int n = rem & 15; rem >>= 4;
    int p = rem & 1;  rem >>= 1;
    int ct = rem % NCT;
    int l = rem / NCT;
    int ks = kpos >> 5, r = kpos & 31;
    int b = (r >> 3) & 3, half = (r >> 2) & 1, j = r & 3;
    int k = ks*32 + half*16 + b*4 + j;
    int col = ct*16 + n;
    float val = 0.f;
    if (k < 75){
      if (col < 375){
        int t = col/75, f = col - t*75;
        val = preW[((size_t)(l*NT + t)*150 + 75 + k)*75 + f];
      } else if (col >= 384 && col < 759){
        int jj = col - 384; int t = jj/75, f = jj - t*75;
        val = preW[((size_t)(l*NT + t)*150 + k)*75 + f];
      } else if (col >= 768 && col < 843){
        int jj = col - 768; int t = jj/15, f2 = jj - t*15;
        val = postW[((size_t)(l*NT + t)*975 + k)*15 + f2];
      }
    }
    unsigned short hi = f2bf(val);
    unsigned short outv = hi;
    if (p){
      float rsd = val - __uint_as_float(((unsigned)hi) << 16);
      outv = f2bf(rsd);
    }
    WgS[idx] = outv;
  }
}

// ------ GEMM1 (MFMA): [B(bf16)|base(+preb)|y0] = src(BN?) @ W.  M=10000,K=75
__global__ __launch_bounds__(256) void k_gemm1(const float* __restrict__ src,
    const unsigned short* __restrict__ WgS, const float* __restrict__ preb,
    const float* __restrict__ bnSp, const float* __restrict__ sc,
    const float* __restrict__ bb, int use_bn,
    unsigned short* __restrict__ out1b, float* __restrict__ baseb,
    float* __restrict__ z, int l){
  __shared__ unsigned short Ah[64*A1STR];
  __shared__ unsigned short Al[64*A1STR];
  int tid = threadIdx.x;
  int bid = blockIdx.x;
  int cg = bid / 157, nt = bid - cg*157;
  int n0 = nt*64;

  for (int i = tid; i < 64*A1STR/2; i += 256){
    ((unsigned*)Ah)[i] = 0; ((unsigned*)Al)[i] = 0;
  }
  __syncthreads();
  for (int idx = tid; idx < 64*75; idx += 256){
    int i = idx/75, c = idx - i*75;
    float v = (n0 + i < NN) ? src[(size_t)n0*75 + idx] : 0.f;
    if (use_bn){
      float mu = bnSp[c] * (1.f/NN);
      float var = bnSp[80 + c] * (1.f/NN) - mu*mu;
      v = fmaxf((v - mu) / sqrtf(var + 1e-5f) * sc[c] + bb[c], 0.f);
    }
    unsigned short hi = f2bf(v);
    float rsd = v - __uint_as_float(((unsigned)hi) << 16);
    int p = i*A1STR + swzk(c);
    Ah[p] = hi; Al[p] = f2bf(rsd);
  }
  __syncthreads();

  int w = tid >> 6, lane = tid & 63;
  int bq = lane >> 4, low = lane & 15;
  const unsigned short* ah = &Ah[(w*16 + low)*A1STR];
  const unsigned short* al = &Al[(w*16 + low)*A1STR];

  float4v acc[8];
  #pragma unroll
  for (int ct = 0; ct < 8; ++ct) acc[ct] = (float4v){0.f,0.f,0.f,0.f};

  #pragma unroll
  for (int ks = 0; ks < 3; ++ks){
    int o = ks*32 + bq*8;
    short8v a_h = ld8(ah + o);
    short8v a_l = ld8(al + o);
    #pragma unroll
    for (int ct = 0; ct < 8; ++ct){
      int gct = cg*8 + ct;
      const unsigned short* wbase = WgS + (((size_t)l*NCT + gct)*2)*16*96 + low*96 + o;
      short8v b_h = ld8(wbase);
      short8v b_l = ld8(wbase + 16*96);
      acc[ct] = __builtin_amdgcn_mfma_f32_16x16x32_bf16(a_h, b_h, acc[ct], 0, 0, 0);
      acc[ct] = __builtin_amdgcn_mfma_f32_16x16x32_bf16(a_h, b_l, acc[ct], 0, 0, 0);
      acc[ct] = __builtin_amdgcn_mfma_f32_16x16x32_bf16(a_l, b_h, acc[ct], 0, 0, 0);
    }
  }

  #pragma unroll
  for (int ct = 0; ct < 8; ++ct){
    int col = cg*128 + ct*16 + low;
    #pragma unroll
    for (int i = 0; i < 4; ++i){
      int n = n0 + w*16 + bq*4 + i;
      if (n < NN){
        float v = acc[ct][i];
        if (col < 375){
          int t = col/75, u = col - t*75;
          out1b[(size_t)n*ROWP + t*80 + u] = f2bf(v);
        } else if (col >= 384 && col < 759){
          int f = col - 384; int t = f/75, u = f - t*75;
          baseb[(size_t)n*ROWP + t*80 + u] = v + preb[l*375 + f];
        } else if (col >= 768 && col < 843){
          z[(size_t)n*75 + (col - 768)] = v;
        }
      }
    }
  }
}

// ---- gather-aggregate: 1 wave / node; lanes 0..49 own 8 padded feats.
// Pads (u>=75, never written by gemm1; 0xAA poison = -3e-13 finite) are
// masked to 0 AFTER stats -> no pad init needed.
__device__ __forceinline__ uint2 pack4(const float* v){
  uint2 r;
  r.x = (unsigned)f2bf(v[0]) | ((unsigned)f2bf(v[1]) << 16);
  r.y = (unsigned)f2bf(v[2]) | ((unsigned)f2bf(v[3]) << 16);
  return r;
}

__global__ __launch_bounds__(256) void k_gather(
    const unsigned short* __restrict__ out1b, const float* __restrict__ baseb,
    const int* __restrict__ off, const int* __restrict__ csr,
    unsigned short* __restrict__ agg){
  int gid = blockIdx.x*256 + threadIdx.x;
  int n = gid >> 6;
  int lane = gid & 63;
  if (n >= NN || lane >= 50) return;
  int p = lane*8;
  int t = p/80, u0 = p - t*80;        // 8 | 80 -> no tower straddle
  float s[8], ss[8], mn[8], mx[8];
  #pragma unroll
  for (int j = 0; j < 8; ++j){ s[j]=0.f; ss[j]=0.f; mn[j]=3.4e38f; mx[j]=-3.4e38f; }
  int e0 = off[n], e1 = off[n+1], deg = e1 - e0;

#define STT(v,J){ float _v=(v); s[J]+=_v; ss[J]+=_v*_v; mn[J]=fminf(mn[J],_v); mx[J]=fmaxf(mx[J],_v); }
#define PR(X){ STT(blo((X).x),0) STT(bhi((X).x),1) STT(blo((X).y),2) STT(bhi((X).y),3) \
               STT(blo((X).z),4) STT(bhi((X).z),5) STT(blo((X).w),6) STT(bhi((X).w),7) }
  int k = e0;
  for (; k + 8 <= e1; k += 8){
    uint4 v0 = *(const uint4*)(out1b + (size_t)csr[k]  *ROWP + p);
    uint4 v1 = *(const uint4*)(out1b + (size_t)csr[k+1]*ROWP + p);
    uint4 v2 = *(const uint4*)(out1b + (size_t)csr[k+2]*ROWP + p);
    uint4 v3 = *(const uint4*)(out1b + (size_t)csr[k+3]*ROWP + p);
    uint4 v4 = *(const uint4*)(out1b + (size_t)csr[k+4]*ROWP + p);
    uint4 v5 = *(const uint4*)(out1b + (size_t)csr[k+5]*ROWP + p);
    uint4 v6 = *(const uint4*)(out1b + (size_t)csr[k+6]*ROWP + p);
    uint4 v7 = *(const uint4*)(out1b + (size_t)csr[k+7]*ROWP + p);
    PR(v0) PR(v1) PR(v2) PR(v3) PR(v4) PR(v5) PR(v6) PR(v7)
  }
  for (; k + 2 <= e1; k += 2){
    uint4 v0 = *(const uint4*)(out1b + (size_t)csr[k]  *ROWP + p);
    uint4 v1 = *(const uint4*)(out1b + (size_t)csr[k+1]*ROWP + p);
    PR(v0) PR(v1)
  }
  if (k < e1){
    uint4 v0 = *(const uint4*)(out1b + (size_t)csr[k]*ROWP + p);
    PR(v0)
  }
#undef PR
#undef STT

  float mean[8], sd[8];
  if (deg > 0){
    float rd = 1.f/(float)deg;
    float4 b0 = *(const float4*)(baseb + (size_t)n*ROWP + p);
    float4 b1 = *(const float4*)(baseb + (size_t)n*ROWP + p + 4);
    float bs[8] = {b0.x,b0.y,b0.z,b0.w,b1.x,b1.y,b1.z,b1.w};
    #pragma unroll
    for (int j = 0; j < 8; ++j){
      float mb = s[j]*rd;
      float var = ss[j]*rd - mb*mb;
      mean[j] = bs[j] + mb;
      sd[j]   = sqrtf(fmaxf(var, 0.f) + 1e-5f);
      mn[j]   = bs[j] + mn[j];
      mx[j]   = bs[j] + mx[j];
    }
  } else {
    #pragma unroll
    for (int j = 0; j < 8; ++j){ mean[j]=0.f; mn[j]=0.f; mx[j]=0.f; sd[j]=sqrtf(1e-5f); }
  }
  // mask pad features (u >= 75) to 0 — squashes uninitialized-pad garbage too
  #pragma unroll
  for (int j = 0; j < 8; ++j){
    if (u0 + j >= 75){ mean[j]=0.f; mn[j]=0.f; mx[j]=0.f; sd[j]=0.f; }
  }
  unsigned short* ap = agg + (size_t)n*1600 + t*320;
  *(uint2*)(ap + swzk(0*80 + u0))     = pack4(mean);
  *(uint2*)(ap + swzk(0*80 + u0 + 4)) = pack4(mean + 4);
  *(uint2*)(ap + swzk(1*80 + u0))     = pack4(mn);
  *(uint2*)(ap + swzk(1*80 + u0 + 4)) = pack4(mn + 4);
  *(uint2*)(ap + swzk(2*80 + u0))     = pack4(mx);
  *(uint2*)(ap + swzk(2*80 + u0 + 4)) = pack4(mx + 4);
  *(uint2*)(ap + swzk(3*80 + u0))     = pack4(sd);
  *(uint2*)(ap + swzk(3*80 + u0 + 4)) = pack4(sd + 4);
}

// ---- post (MFMA, no LDS staging): block = 128 thr = 2 waves.
__global__ __launch_bounds__(128) void k_post(
    const unsigned short* __restrict__ agg, float* __restrict__ z,
    const int* __restrict__ off, const unsigned short* __restrict__ W45S,
    const float* __restrict__ postb, int l){
  __shared__ float ampl[32], attl[32];
  int tid = threadIdx.x;
  int bid = blockIdx.x;
  const int NTILE = (NN + 31)/32;          // 313
  int t = bid / NTILE, nt = bid - t*NTILE;
  int n0 = nt*32;
  if (tid < 32){
    int n = n0 + tid;
    int dd = (n < NN) ? (off[n+1] - off[n]) : 1;
    float d = (float)(dd > 0 ? dd : 1);
    float logd = logf(d + 1.f);
    ampl[tid] = logd*(1.f/LOG17);
    attl[tid] = LOG17/logd;
  }
  __syncthreads();

  int w = tid >> 6, lane = tid & 63;
  int bq = lane >> 4, low = lane & 15;
  int node = n0 + w*16 + low;
  int ncl = (node < NN) ? node : (NN - 1);
  const unsigned short* ab = agg + (size_t)ncl*1600 + t*320;
  const unsigned short* wb = W45S + (size_t)((l*NT + t)*3)*2*16*320;
  const unsigned short* b0h = wb + (size_t)(0*2+0)*16*320 + low*320;
  const unsigned short* b0l = wb + (size_t)(0*2+1)*16*320 + low*320;
  const unsigned short* b1h = wb + (size_t)(1*2+0)*16*320 + low*320;
  const unsigned short* b1l = wb + (size_t)(1*2+1)*16*320 + low*320;
  const unsigned short* b2h = wb + (size_t)(2*2+0)*16*320 + low*320;
  const unsigned short* b2l = wb + (size_t)(2*2+1)*16*320 + low*320;

  float4v acc0 = {0.f,0.f,0.f,0.f};
  float4v acc1 = {0.f,0.f,0.f,0.f};
  float4v acc2 = {0.f,0.f,0.f,0.f};
  #pragma unroll
  for (int ks = 0; ks < 10; ++ks){
    int o = ks*32 + bq*8;
    short8v a = ld8(ab + o);
    acc0 = __builtin_amdgcn_mfma_f32_16x16x32_bf16(a, ld8(b0h + o), acc0, 0, 0, 0);
    acc1 = __builtin_amdgcn_mfma_f32_16x16x32_bf16(a, ld8(b1h + o), acc1, 0, 0, 0);
    acc2 = __builtin_amdgcn_mfma_f32_16x16x32_bf16(a, ld8(b2h + o), acc2, 0, 0, 0);
    acc0 = __builtin_amdgcn_mfma_f32_16x16x32_bf16(a, ld8(b0l + o), acc0, 0, 0, 0);
    acc1 = __builtin_amdgcn_mfma_f32_16x16x32_bf16(a, ld8(b1l + o), acc1, 0, 0, 0);
    acc2 = __builtin_amdgcn_mfma_f32_16x16x32_bf16(a, ld8(b2l + o), acc2, 0, 0, 0);
  }

  if (low < 15){
    float pb = postb[(l*NT + t)*15 + low];
    #pragma unroll
    for (int i = 0; i < 4; ++i){
      int m = bq*4 + i;
      int nd = n0 + w*16 + m;
      if (nd < NN){
        float val = acc0[i] + ampl[w*16 + m]*acc1[i] + attl[w*16 + m]*acc2[i] + pb;
        z[(size_t)nd*75 + t*15 + low] += val;
      }
    }
  }
}

// ------ mixing lin (32 nodes/block, grid 313): out2 = z @ linW + linb + BN sums
__global__ __launch_bounds__(256) void k_lin(const float* __restrict__ z,
    const float* __restrict__ linW, const float* __restrict__ linb,
    float* __restrict__ out2, float* __restrict__ bnS1, int l){
  __shared__ float zs[75][36];
  __shared__ float lw[75][80];
  int tid = threadIdx.x;
  int n0 = blockIdx.x*32;
  for (int idx = tid; idx < 32*75; idx += 256){
    int i = idx/75, c = idx - i*75;
    zs[c][i] = (n0 + i < NN) ? z[(size_t)n0*75 + idx] : 0.f;
  }
  for (int idx = tid; idx < 75*80; idx += 256){
    int c = idx/80, o = idx - c*80;
    lw[c][o] = (o < 75) ? linW[(size_t)l*5625 + c*75 + o] : 0.f;
  }
  __syncthreads();
  int og = tid >> 4, n4 = tid & 15;    // og 0..15 (5 outs), n4 0..15 (2 nodes)
  int o0 = og*5;
  float acc[2][5];
  #pragma unroll
  for (int i = 0; i < 2; ++i)
    #pragma unroll
    for (int k = 0; k < 5; ++k) acc[i][k] = 0.f;
  for (int c = 0; c < 75; ++c){
    float2 a = *reinterpret_cast<const float2*>(&zs[c][n4*2]);
    float av[2] = {a.x, a.y};
    float wv[5];
    #pragma unroll
    for (int k = 0; k < 5; ++k) wv[k] = lw[c][o0 + k];
    #pragma unroll
    for (int i = 0; i < 2; ++i)
      #pragma unroll
      for (int k = 0; k < 5; ++k) acc[i][k] += av[i]*wv[k];
  }
  float s1p[5], s2p[5];
  #pragma unroll
  for (int k = 0; k < 5; ++k){ s1p[k] = 0.f; s2p[k] = 0.f; }
  #pragma unroll
  for (int i = 0; i < 2; ++i){
    int n = n0 + n4*2 + i;
    if (n >= NN) continue;
    #pragma unroll
    for (int k = 0; k < 5; ++k){
      int o = o0 + k;
      if (o < 75){
        float v = acc[i][k] + linb[l*75 + o];
        out2[(size_t)n*75 + o] = v;
        s1p[k] += v; s2p[k] += v*v;
      }
    }
  }
  __syncthreads();
  float* red = &zs[0][0];          // [75][16] s1, then [75][16] s2 (2400 < 2700)
  #pragma unroll
  for (int k = 0; k < 5; ++k){
    int o = o0 + k;
    if (o < 75){ red[o*16 + n4] = s1p[k]; red[1200 + o*16 + n4] = s2p[k]; }
  }
  __syncthreads();
  if (tid < 75){
    float a1 = 0.f, a2 = 0.f;
    #pragma unroll
    for (int j = 0; j < 16; ++j){ a1 += red[tid*16 + j]; a2 += red[1200 + tid*16 + j]; }
    atomicAdd(&bnS1[tid], a1);
    atomicAdd(&bnS1[80 + tid], a2);
  }
}

// -------------------------------- final BN+ReLU fused with global_add_pool
__global__ __launch_bounds__(256) void k_bnpool(const float* __restrict__ out2,
    const float* __restrict__ bnSp, const float* __restrict__ sc,
    const float* __restrict__ bb, const int* __restrict__ batch,
    float* __restrict__ pooled){
  int i = blockIdx.x*256 + threadIdx.x;
  if (i >= NN*75) return;
  int n = i / 75, f = i - n*75;
  float mu = bnSp[f] * (1.f/NN);
  float var = bnSp[80 + f] * (1.f/NN) - mu*mu;
  float v = fmaxf((out2[i] - mu) / sqrtf(var + 1e-5f) * sc[f] + bb[f], 0.f);
  atomicAdd(&pooled[batch[n]*75 + f], v);
}

__global__ __launch_bounds__(256) void k_head(const float* __restrict__ pooled,
    const float* __restrict__ W1, const float* __restrict__ b1,
    const float* __restrict__ W2, const float* __restrict__ b2,
    const float* __restrict__ W3, const float* __restrict__ b3,
    float* __restrict__ out){
  __shared__ float pl[64*75];
  __shared__ float w1[75*50];
  __shared__ float z1[64*50];
  __shared__ float w2[50*25];
  __shared__ float z2[64*25];
  __shared__ float w3[25];
  __shared__ float bb1[50], bb2[25];
  int tid = threadIdx.x;
  for (int i = tid; i < 64*75; i += 256) pl[i] = pooled[i];
  for (int i = tid; i < 75*50; i += 256) w1[i] = W1[i];
  for (int i = tid; i < 50*25; i += 256) w2[i] = W2[i];
  if (tid < 25) w3[tid] = W3[tid];
  if (tid < 50) bb1[tid] = b1[tid];
  if (tid < 25) bb2[tid] = b2[tid];
  __syncthreads();
  for (int o = tid; o < 64*50; o += 256){
    int g = o / 50, j = o - g*50;
    float acc = bb1[j];
    for (int c = 0; c < 75; ++c) acc += pl[g*75 + c] * w1[c*50 + j];
    z1[o] = fmaxf(acc, 0.f);
  }
  __syncthreads();
  for (int o = tid; o < 64*25; o += 256){
    int g = o / 25, j = o - g*25;
    float acc = bb2[j];
    for (int c = 0; c < 50; ++c) acc += z1[g*50 + c] * w2[c*25 + j];
    z2[o] = fmaxf(acc, 0.f);
  }
  __syncthreads();
  if (tid < 64){
    float acc = b3[0];
    for (int c = 0; c < 25; ++c) acc += z2[tid*25 + c] * w3[c];
    out[tid] = acc;
  }
}

// ---------------------------------------------------------------- launcher
extern "C" void kernel_launch(void* const* d_in, const int* in_sizes, int n_in,
                              void* d_out, int out_size, void* d_ws, size_t ws_size,
                              hipStream_t stream){
  const float* x     = (const float*)d_in[0];
  const int*   ei    = (const int*)  d_in[1];
  const int*   batch = (const int*)  d_in[2];
  const float* plW   = (const float*)d_in[3];
  const float* plb   = (const float*)d_in[4];
  const float* preW  = (const float*)d_in[5];
  const float* preb  = (const float*)d_in[6];
  const float* postW = (const float*)d_in[7];
  const float* postb = (const float*)d_in[8];
  const float* linW  = (const float*)d_in[9];
  const float* linb  = (const float*)d_in[10];
  const float* bns   = (const float*)d_in[11];
  const float* bnb   = (const float*)d_in[12];
  const float* W1    = (const float*)d_in[13];
  const float* b1    = (const float*)d_in[14];
  const float* W2    = (const float*)d_in[15];
  const float* b2    = (const float*)d_in[16];
  const float* W3    = (const float*)d_in[17];
  const float* b3    = (const float*)d_in[18];
  float* out = (float*)d_out;

  // workspace layout (~76.4 MB)
  float* out2v = (float*)d_ws;                     // 750000
  float* zv    = out2v + 750000;                   // 750000
  float* baseb = zv + 750000;                      // NN*400 f32 = 16 MB
  unsigned short* W45S = (unsigned short*)(baseb + (size_t)NN*ROWP); // 614,400
  unsigned short* WgS  = W45S + (size_t)TOTW45;                      // 688,128
  float* pooled= (float*)(WgS + (size_t)TOTWG);                      // 4800
  float* bnS   = pooled + 4800;                    // 4*160
  unsigned short* out1b = (unsigned short*)(bnS + NL*160);  // NN*400
  unsigned short* aggb  = out1b + (size_t)NN*ROWP;          // NN*1600 = 32 MB
  // h0 aliases the TAIL of aggb: used only before the first k_gather write.
  float* h0 = (float*)(aggb + (size_t)NN*1600) - 750000;
  int* cnt = (int*)(aggb + (size_t)NN*1600);
  int* off = cnt + NN;
  int* cur = off + NN + 1;
  int* csr = cur + NN;

  k_init<<<(NN*NF + 255)/256, 256, 0, stream>>>(x, plW, plb, h0, cnt, bnS, pooled);
  k_count<<<(NE + 255)/256, 256, 0, stream>>>(ei, cnt);
  k_scan<<<1, 1024, 0, stream>>>(cnt, off, cur);
  k_scatter<<<(NE + 255)/256, 256, 0, stream>>>(ei, cur, csr);
  k_build<<<(TOTWG + 255)/256, 256, 0, stream>>>(preW, postW, W45S, WgS);

  const int NTILE = (NN + 31)/32;   // 313

  for (int l = 0; l < NL; ++l){
    const float* src = (l == 0) ? h0 : out2v;
    const float* bnSp = bnS + (l > 0 ? (l-1)*160 : 0);
    const float* sc = bns + (l > 0 ? (l-1)*75 : 0);
    const float* bb = bnb + (l > 0 ? (l-1)*75 : 0);
    k_gemm1<<<7*157, 256, 0, stream>>>(src, WgS, preb, bnSp, sc, bb, (l > 0),
                                       out1b, baseb, zv, l);
    k_gather<<<(NN*64)/256, 256, 0, stream>>>(out1b, baseb, off, csr, aggb);
    k_post<<<NT*NTILE, 128, 0, stream>>>(aggb, zv, off, W45S, postb, l);
    k_lin<<<NTILE, 256, 0, stream>>>(zv, linW, linb, out2v, bnS + l*160, l);
  }

  k_bnpool<<<(NN*NF + 255)/256, 256, 0, stream>>>(out2v, bnS + 3*160,
                                                  bns + 3*75, bnb + 3*75, batch, pooled);
  k_head<<<1, 256, 0, stream>>>(pooled, W1, b1, W2, b2, W3, b3, out);
}

// Round 19
// 547.901 us; speedup vs baseline: 1.3285x; 1.3285x over previous
//
#include <hip/hip_runtime.h>

#define NN 10000
#define NE 160000
#define NG 64
#define NT 5
#define NF 75
#define NL 4
#define LOG17 2.8332133f  /* log(17.0) */
#define ROWP 400          /* out1b/baseb padded row: 5 towers x 80 */
#define A1STR 104         /* k_gemm1 LDS A row stride */
#define NCT 56            /* WgS col-tiles (843 used, padded to 56*16=896) */
#define TOTW45 (NL*NT*3*2*16*320)   /* 614,400 */
#define TOTWG  (NL*NCT*2*16*96)     /* 688,128 — grid covers max of both */

typedef __attribute__((ext_vector_type(8))) short short8v;
typedef __attribute__((ext_vector_type(4))) float float4v;

__device__ __forceinline__ unsigned short f2bf(float x){
  unsigned u = __float_as_uint(x);
  unsigned r = (u + 0x7FFFu + ((u >> 16) & 1u)) >> 16;
  return (unsigned short)r;
}
__device__ __forceinline__ float blo(unsigned u){ return __uint_as_float(u << 16); }
__device__ __forceinline__ float bhi(unsigned u){ return __uint_as_float(u & 0xFFFF0000u); }

// MFMA 16x16x32 bf16 fragment k-order: pos = ks*32 + b*8 + half*4 + j
__device__ __forceinline__ int swzk(int k){
  int ks = k >> 5, r = k & 31;
  return (ks << 5) | (((r & 15) >> 2) << 3) | ((r >> 4) << 2) | (r & 3);
}
__device__ __forceinline__ short8v ld8(const unsigned short* p){
  union { uint4 u; short8v v; } x;
  x.u = *(const uint4*)p;
  return x.v;
}

// ------------- setup: h init + zero cnt/bnS/pooled
__global__ __launch_bounds__(256) void k_init(const float* __restrict__ x,
    const float* __restrict__ W, const float* __restrict__ b, float* __restrict__ h,
    int* __restrict__ cnt, float* __restrict__ bnS, float* __restrict__ pooled){
  int i = blockIdx.x*256 + threadIdx.x;
  if (i < NN) cnt[i] = 0;
  if (i < NL*160) bnS[i] = 0.f;
  if (i < NG*75) pooled[i] = 0.f;
  if (i >= NN*NF) return;
  int n = i / NF, f = i - n*NF;
  h[i] = x[2*n]*W[f] + x[2*n+1]*W[NF+f] + b[f];
}

__global__ __launch_bounds__(256) void k_count(const int* __restrict__ ei, int* __restrict__ cnt){
  int e = blockIdx.x*256 + threadIdx.x;
  if (e < NE) atomicAdd(&cnt[ei[NE + e]], 1);   // row 1 = dst
}

// 1-block scan, thread owns 10 contiguous nodes.
__global__ __launch_bounds__(1024) void k_scan(const int* __restrict__ cnt,
    int* __restrict__ off, int* __restrict__ cur){
  __shared__ int buf[1024];
  int tid = threadIdx.x;
  int base = tid*10;
  int loc[10];
  int s = 0;
  #pragma unroll
  for (int j = 0; j < 10; ++j){
    int i = base + j;
    loc[j] = s;
    s += (i < NN) ? cnt[i] : 0;
  }
  buf[tid] = s;
  __syncthreads();
  for (int d = 1; d < 1024; d <<= 1){
    int t = (tid >= d) ? buf[tid - d] : 0;
    __syncthreads();
    buf[tid] += t;
    __syncthreads();
  }
  int ex = buf[tid] - s;
  #pragma unroll
  for (int j = 0; j < 10; ++j){
    int i = base + j;
    if (i < NN){ int v = ex + loc[j]; off[i] = v; cur[i] = v; }
  }
  if (tid == 1023) off[NN] = ex + s;
}

__global__ __launch_bounds__(256) void k_scatter(const int* __restrict__ ei,
    int* __restrict__ cur, int* __restrict__ csr){
  int e = blockIdx.x*256 + threadIdx.x;
  if (e < NE){
    int d = ei[NE + e];
    int p = atomicAdd(&cur[d], 1);
    csr[p] = ei[e];   // src node
  }
}

// merged weight build: grid covers max(TOTW45, TOTWG) = TOTWG.
__global__ __launch_bounds__(256) void k_build(const float* __restrict__ preW,
    const float* __restrict__ postW, unsigned short* __restrict__ W45S,
    unsigned short* __restrict__ WgS){
  int idx = blockIdx.x*256 + threadIdx.x;
  if (idx < TOTW45){
    int kpos = idx % 320;
    int rem = idx / 320;
    int n = rem & 15; rem >>= 4;
    int p = rem & 1;  rem >>= 1;
    int g = rem % 3;  rem /= 3;
    int t = rem % 5;
    int l = rem / 5;
    int ks = kpos >> 5, r = kpos & 31;
    int b = (r >> 3) & 3, half = (r >> 2) & 1, j = r & 3;
    int kp = ks*32 + half*16 + b*4 + j;
    int stat = kp / 80, u = kp - stat*80;
    float val = 0.f;
    if (n < 15 && u < 75)
      val = postW[((size_t)(l*NT + t)*975 + 75 + g*300 + stat*75 + u)*15 + n];
    unsigned short hi = f2bf(val);
    unsigned short outv = hi;
    if (p){
      float rsd = val - __uint_as_float(((unsigned)hi) << 16);
      outv = f2bf(rsd);
    }
    W45S[idx] = outv;
  }
  if (idx < TOTWG){
    int kpos = idx % 96;
    int rem = idx / 96;
    int n = rem & 15; rem >>= 4;
    int p = rem & 1;  rem >>= 1;
    int ct = rem % NCT;
    int l = rem / NCT;
    int ks = kpos >> 5, r = kpos & 31;
    int b = (r >> 3) & 3, half = (r >> 2) & 1, j = r & 3;
    int k = ks*32 + half*16 + b*4 + j;
    int col = ct*16 + n;
    float val = 0.f;
    if (k < 75){
      if (col < 375){
        int t = col/75, f = col - t*75;
        val = preW[((size_t)(l*NT + t)*150 + 75 + k)*75 + f];
      } else if (col >= 384 && col < 759){
        int jj = col - 384; int t = jj/75, f = jj - t*75;
        val = preW[((size_t)(l*NT + t)*150 + k)*75 + f];
      } else if (col >= 768 && col < 843){
        int jj = col - 768; int t = jj/15, f2 = jj - t*15;
        val = postW[((size_t)(l*NT + t)*975 + k)*15 + f2];
      }
    }
    unsigned short hi = f2bf(val);
    unsigned short outv = hi;
    if (p){
      float rsd = val - __uint_as_float(((unsigned)hi) << 16);
      outv = f2bf(rsd);
    }
    WgS[idx] = outv;
  }
}

// ------ GEMM1 (MFMA): [B(bf16)|base(+preb)|y0] = src(BN?) @ W.  M=10000,K=75
__global__ __launch_bounds__(256) void k_gemm1(const float* __restrict__ src,
    const unsigned short* __restrict__ WgS, const float* __restrict__ preb,
    const float* __restrict__ bnSp, const float* __restrict__ sc,
    const float* __restrict__ bb, int use_bn,
    unsigned short* __restrict__ out1b, float* __restrict__ baseb,
    float* __restrict__ z, int l){
  __shared__ unsigned short Ah[64*A1STR];
  __shared__ unsigned short Al[64*A1STR];
  int tid = threadIdx.x;
  int bid = blockIdx.x;
  int cg = bid / 157, nt = bid - cg*157;
  int n0 = nt*64;

  for (int i = tid; i < 64*A1STR/2; i += 256){
    ((unsigned*)Ah)[i] = 0; ((unsigned*)Al)[i] = 0;
  }
  __syncthreads();
  for (int idx = tid; idx < 64*75; idx += 256){
    int i = idx/75, c = idx - i*75;
    float v = (n0 + i < NN) ? src[(size_t)n0*75 + idx] : 0.f;
    if (use_bn){
      float mu = bnSp[c] * (1.f/NN);
      float var = bnSp[80 + c] * (1.f/NN) - mu*mu;
      v = fmaxf((v - mu) / sqrtf(var + 1e-5f) * sc[c] + bb[c], 0.f);
    }
    unsigned short hi = f2bf(v);
    float rsd = v - __uint_as_float(((unsigned)hi) << 16);
    int p = i*A1STR + swzk(c);
    Ah[p] = hi; Al[p] = f2bf(rsd);
  }
  __syncthreads();

  int w = tid >> 6, lane = tid & 63;
  int bq = lane >> 4, low = lane & 15;
  const unsigned short* ah = &Ah[(w*16 + low)*A1STR];
  const unsigned short* al = &Al[(w*16 + low)*A1STR];

  float4v acc[8];
  #pragma unroll
  for (int ct = 0; ct < 8; ++ct) acc[ct] = (float4v){0.f,0.f,0.f,0.f};

  #pragma unroll
  for (int ks = 0; ks < 3; ++ks){
    int o = ks*32 + bq*8;
    short8v a_h = ld8(ah + o);
    short8v a_l = ld8(al + o);
    #pragma unroll
    for (int ct = 0; ct < 8; ++ct){
      int gct = cg*8 + ct;
      const unsigned short* wbase = WgS + (((size_t)l*NCT + gct)*2)*16*96 + low*96 + o;
      short8v b_h = ld8(wbase);
      short8v b_l = ld8(wbase + 16*96);
      acc[ct] = __builtin_amdgcn_mfma_f32_16x16x32_bf16(a_h, b_h, acc[ct], 0, 0, 0);
      acc[ct] = __builtin_amdgcn_mfma_f32_16x16x32_bf16(a_h, b_l, acc[ct], 0, 0, 0);
      acc[ct] = __builtin_amdgcn_mfma_f32_16x16x32_bf16(a_l, b_h, acc[ct], 0, 0, 0);
    }
  }

  #pragma unroll
  for (int ct = 0; ct < 8; ++ct){
    int col = cg*128 + ct*16 + low;
    #pragma unroll
    for (int i = 0; i < 4; ++i){
      int n = n0 + w*16 + bq*4 + i;
      if (n < NN){
        float v = acc[ct][i];
        if (col < 375){
          int t = col/75, u = col - t*75;
          out1b[(size_t)n*ROWP + t*80 + u] = f2bf(v);
        } else if (col >= 384 && col < 759){
          int f = col - 384; int t = f/75, u = f - t*75;
          baseb[(size_t)n*ROWP + t*80 + u] = v + preb[l*375 + f];
        } else if (col >= 768 && col < 843){
          z[(size_t)n*75 + (col - 768)] = v;
        }
      }
    }
  }
}

// ---- gather-aggregate: 1 wave / node; lanes 0..49 own 8 padded feats.
// Pads (u>=75) masked to 0 AFTER stats -> no pad init needed (validated R18).
__device__ __forceinline__ uint2 pack4(const float* v){
  uint2 r;
  r.x = (unsigned)f2bf(v[0]) | ((unsigned)f2bf(v[1]) << 16);
  r.y = (unsigned)f2bf(v[2]) | ((unsigned)f2bf(v[3]) << 16);
  return r;
}

__global__ __launch_bounds__(256) void k_gather(
    const unsigned short* __restrict__ out1b, const float* __restrict__ baseb,
    const int* __restrict__ off, const int* __restrict__ csr,
    unsigned short* __restrict__ agg){
  int gid = blockIdx.x*256 + threadIdx.x;
  int n = gid >> 6;
  int lane = gid & 63;
  if (n >= NN || lane >= 50) return;
  int p = lane*8;
  int t = p/80, u0 = p - t*80;        // 8 | 80 -> no tower straddle
  float s[8], ss[8], mn[8], mx[8];
  #pragma unroll
  for (int j = 0; j < 8; ++j){ s[j]=0.f; ss[j]=0.f; mn[j]=3.4e38f; mx[j]=-3.4e38f; }
  int e0 = off[n], e1 = off[n+1], deg = e1 - e0;

#define STT(v,J){ float _v=(v); s[J]+=_v; ss[J]+=_v*_v; mn[J]=fminf(mn[J],_v); mx[J]=fmaxf(mx[J],_v); }
#define PR(X){ STT(blo((X).x),0) STT(bhi((X).x),1) STT(blo((X).y),2) STT(bhi((X).y),3) \
               STT(blo((X).z),4) STT(bhi((X).z),5) STT(blo((X).w),6) STT(bhi((X).w),7) }
  int k = e0;
  for (; k + 8 <= e1; k += 8){
    uint4 v0 = *(const uint4*)(out1b + (size_t)csr[k]  *ROWP + p);
    uint4 v1 = *(const uint4*)(out1b + (size_t)csr[k+1]*ROWP + p);
    uint4 v2 = *(const uint4*)(out1b + (size_t)csr[k+2]*ROWP + p);
    uint4 v3 = *(const uint4*)(out1b + (size_t)csr[k+3]*ROWP + p);
    uint4 v4 = *(const uint4*)(out1b + (size_t)csr[k+4]*ROWP + p);
    uint4 v5 = *(const uint4*)(out1b + (size_t)csr[k+5]*ROWP + p);
    uint4 v6 = *(const uint4*)(out1b + (size_t)csr[k+6]*ROWP + p);
    uint4 v7 = *(const uint4*)(out1b + (size_t)csr[k+7]*ROWP + p);
    PR(v0) PR(v1) PR(v2) PR(v3) PR(v4) PR(v5) PR(v6) PR(v7)
  }
  for (; k + 2 <= e1; k += 2){
    uint4 v0 = *(const uint4*)(out1b + (size_t)csr[k]  *ROWP + p);
    uint4 v1 = *(const uint4*)(out1b + (size_t)csr[k+1]*ROWP + p);
    PR(v0) PR(v1)
  }
  if (k < e1){
    uint4 v0 = *(const uint4*)(out1b + (size_t)csr[k]*ROWP + p);
    PR(v0)
  }
#undef PR
#undef STT

  float mean[8], sd[8];
  if (deg > 0){
    float rd = 1.f/(float)deg;
    float4 b0 = *(const float4*)(baseb + (size_t)n*ROWP + p);
    float4 b1 = *(const float4*)(baseb + (size_t)n*ROWP + p + 4);
    float bs[8] = {b0.x,b0.y,b0.z,b0.w,b1.x,b1.y,b1.z,b1.w};
    #pragma unroll
    for (int j = 0; j < 8; ++j){
      float mb = s[j]*rd;
      float var = ss[j]*rd - mb*mb;
      mean[j] = bs[j] + mb;
      sd[j]   = sqrtf(fmaxf(var, 0.f) + 1e-5f);
      mn[j]   = bs[j] + mn[j];
      mx[j]   = bs[j] + mx[j];
    }
  } else {
    #pragma unroll
    for (int j = 0; j < 8; ++j){ mean[j]=0.f; mn[j]=0.f; mx[j]=0.f; sd[j]=sqrtf(1e-5f); }
  }
  // mask pad features (u >= 75) to 0 — squashes uninitialized-pad garbage too
  #pragma unroll
  for (int j = 0; j < 8; ++j){
    if (u0 + j >= 75){ mean[j]=0.f; mn[j]=0.f; mx[j]=0.f; sd[j]=0.f; }
  }
  unsigned short* ap = agg + (size_t)n*1600 + t*320;
  *(uint2*)(ap + swzk(0*80 + u0))     = pack4(mean);
  *(uint2*)(ap + swzk(0*80 + u0 + 4)) = pack4(mean + 4);
  *(uint2*)(ap + swzk(1*80 + u0))     = pack4(mn);
  *(uint2*)(ap + swzk(1*80 + u0 + 4)) = pack4(mn + 4);
  *(uint2*)(ap + swzk(2*80 + u0))     = pack4(mx);
  *(uint2*)(ap + swzk(2*80 + u0 + 4)) = pack4(mx + 4);
  *(uint2*)(ap + swzk(3*80 + u0))     = pack4(sd);
  *(uint2*)(ap + swzk(3*80 + u0 + 4)) = pack4(sd + 4);
}

// ---- post (MFMA, no LDS staging): block = 128 thr = 2 waves.
__global__ __launch_bounds__(128) void k_post(
    const unsigned short* __restrict__ agg, float* __restrict__ z,
    const int* __restrict__ off, const unsigned short* __restrict__ W45S,
    const float* __restrict__ postb, int l){
  __shared__ float ampl[32], attl[32];
  int tid = threadIdx.x;
  int bid = blockIdx.x;
  const int NTILE = (NN + 31)/32;          // 313
  int t = bid / NTILE, nt = bid - t*NTILE;
  int n0 = nt*32;
  if (tid < 32){
    int n = n0 + tid;
    int dd = (n < NN) ? (off[n+1] - off[n]) : 1;
    float d = (float)(dd > 0 ? dd : 1);
    float logd = logf(d + 1.f);
    ampl[tid] = logd*(1.f/LOG17);
    attl[tid] = LOG17/logd;
  }
  __syncthreads();

  int w = tid >> 6, lane = tid & 63;
  int bq = lane >> 4, low = lane & 15;
  int node = n0 + w*16 + low;
  int ncl = (node < NN) ? node : (NN - 1);
  const unsigned short* ab = agg + (size_t)ncl*1600 + t*320;
  const unsigned short* wb = W45S + (size_t)((l*NT + t)*3)*2*16*320;
  const unsigned short* b0h = wb + (size_t)(0*2+0)*16*320 + low*320;
  const unsigned short* b0l = wb + (size_t)(0*2+1)*16*320 + low*320;
  const unsigned short* b1h = wb + (size_t)(1*2+0)*16*320 + low*320;
  const unsigned short* b1l = wb + (size_t)(1*2+1)*16*320 + low*320;
  const unsigned short* b2h = wb + (size_t)(2*2+0)*16*320 + low*320;
  const unsigned short* b2l = wb + (size_t)(2*2+1)*16*320 + low*320;

  float4v acc0 = {0.f,0.f,0.f,0.f};
  float4v acc1 = {0.f,0.f,0.f,0.f};
  float4v acc2 = {0.f,0.f,0.f,0.f};
  #pragma unroll
  for (int ks = 0; ks < 10; ++ks){
    int o = ks*32 + bq*8;
    short8v a = ld8(ab + o);
    acc0 = __builtin_amdgcn_mfma_f32_16x16x32_bf16(a, ld8(b0h + o), acc0, 0, 0, 0);
    acc1 = __builtin_amdgcn_mfma_f32_16x16x32_bf16(a, ld8(b1h + o), acc1, 0, 0, 0);
    acc2 = __builtin_amdgcn_mfma_f32_16x16x32_bf16(a, ld8(b2h + o), acc2, 0, 0, 0);
    acc0 = __builtin_amdgcn_mfma_f32_16x16x32_bf16(a, ld8(b0l + o), acc0, 0, 0, 0);
    acc1 = __builtin_amdgcn_mfma_f32_16x16x32_bf16(a, ld8(b1l + o), acc1, 0, 0, 0);
    acc2 = __builtin_amdgcn_mfma_f32_16x16x32_bf16(a, ld8(b2l + o), acc2, 0, 0, 0);
  }

  if (low < 15){
    float pb = postb[(l*NT + t)*15 + low];
    #pragma unroll
    for (int i = 0; i < 4; ++i){
      int m = bq*4 + i;
      int nd = n0 + w*16 + m;
      if (nd < NN){
        float val = acc0[i] + ampl[w*16 + m]*acc1[i] + attl[w*16 + m]*acc2[i] + pb;
        z[(size_t)nd*75 + t*15 + low] += val;
      }
    }
  }
}

// ------ mixing lin (64 nodes/block, grid 157 — proven R13-R17 version)
__global__ __launch_bounds__(256) void k_lin(const float* __restrict__ z,
    const float* __restrict__ linW, const float* __restrict__ linb,
    float* __restrict__ out2, float* __restrict__ bnS1, int l){
  __shared__ float zs[75][68];
  __shared__ float lw[75][80];
  int tid = threadIdx.x;
  int n0 = blockIdx.x*64;
  for (int idx = tid; idx < 64*75; idx += 256){
    int i = idx/75, c = idx - i*75;
    zs[c][i] = (n0 + i < NN) ? z[(size_t)n0*75 + idx] : 0.f;
  }
  for (int idx = tid; idx < 75*80; idx += 256){
    int c = idx/80, o = idx - c*80;
    lw[c][o] = (o < 75) ? linW[(size_t)l*5625 + c*75 + o] : 0.f;
  }
  __syncthreads();
  int og = tid >> 4, n4 = tid & 15;
  int o0 = og*5;
  float acc[4][5];
  #pragma unroll
  for (int i = 0; i < 4; ++i)
    #pragma unroll
    for (int k = 0; k < 5; ++k) acc[i][k] = 0.f;
  for (int c = 0; c < 75; ++c){
    float4 a = *reinterpret_cast<const float4*>(&zs[c][n4*4]);
    float av[4] = {a.x, a.y, a.z, a.w};
    float wv[5];
    #pragma unroll
    for (int k = 0; k < 5; ++k) wv[k] = lw[c][o0 + k];
    #pragma unroll
    for (int i = 0; i < 4; ++i)
      #pragma unroll
      for (int k = 0; k < 5; ++k) acc[i][k] += av[i]*wv[k];
  }
  float s1p[5], s2p[5];
  #pragma unroll
  for (int k = 0; k < 5; ++k){ s1p[k] = 0.f; s2p[k] = 0.f; }
  #pragma unroll
  for (int i = 0; i < 4; ++i){
    int n = n0 + n4*4 + i;
    if (n >= NN) continue;
    #pragma unroll
    for (int k = 0; k < 5; ++k){
      int o = o0 + k;
      if (o < 75){
        float v = acc[i][k] + linb[l*75 + o];
        out2[(size_t)n*75 + o] = v;
        s1p[k] += v; s2p[k] += v*v;
      }
    }
  }
  __syncthreads();
  float* red = &zs[0][0];          // [75][16] s1, then [75][16] s2
  #pragma unroll
  for (int k = 0; k < 5; ++k){
    int o = o0 + k;
    if (o < 75){ red[o*16 + n4] = s1p[k]; red[1200 + o*16 + n4] = s2p[k]; }
  }
  __syncthreads();
  if (tid < 75){
    float a1 = 0.f, a2 = 0.f;
    #pragma unroll
    for (int j = 0; j < 16; ++j){ a1 += red[tid*16 + j]; a2 += red[1200 + tid*16 + j]; }
    atomicAdd(&bnS1[tid], a1);
    atomicAdd(&bnS1[80 + tid], a2);
  }
}

// -------------------------------- final BN+ReLU fused with global_add_pool
__global__ __launch_bounds__(256) void k_bnpool(const float* __restrict__ out2,
    const float* __restrict__ bnSp, const float* __restrict__ sc,
    const float* __restrict__ bb, const int* __restrict__ batch,
    float* __restrict__ pooled){
  int i = blockIdx.x*256 + threadIdx.x;
  if (i >= NN*75) return;
  int n = i / 75, f = i - n*75;
  float mu = bnSp[f] * (1.f/NN);
  float var = bnSp[80 + f] * (1.f/NN) - mu*mu;
  float v = fmaxf((out2[i] - mu) / sqrtf(var + 1e-5f) * sc[f] + bb[f], 0.f);
  atomicAdd(&pooled[batch[n]*75 + f], v);
}

__global__ __launch_bounds__(256) void k_head(const float* __restrict__ pooled,
    const float* __restrict__ W1, const float* __restrict__ b1,
    const float* __restrict__ W2, const float* __restrict__ b2,
    const float* __restrict__ W3, const float* __restrict__ b3,
    float* __restrict__ out){
  __shared__ float pl[64*75];
  __shared__ float w1[75*50];
  __shared__ float z1[64*50];
  __shared__ float w2[50*25];
  __shared__ float z2[64*25];
  __shared__ float w3[25];
  __shared__ float bb1[50], bb2[25];
  int tid = threadIdx.x;
  for (int i = tid; i < 64*75; i += 256) pl[i] = pooled[i];
  for (int i = tid; i < 75*50; i += 256) w1[i] = W1[i];
  for (int i = tid; i < 50*25; i += 256) w2[i] = W2[i];
  if (tid < 25) w3[tid] = W3[tid];
  if (tid < 50) bb1[tid] = b1[tid];
  if (tid < 25) bb2[tid] = b2[tid];
  __syncthreads();
  for (int o = tid; o < 64*50; o += 256){
    int g = o / 50, j = o - g*50;
    float acc = bb1[j];
    for (int c = 0; c < 75; ++c) acc += pl[g*75 + c] * w1[c*50 + j];
    z1[o] = fmaxf(acc, 0.f);
  }
  __syncthreads();
  for (int o = tid; o < 64*25; o += 256){
    int g = o / 25, j = o - g*25;
    float acc = bb2[j];
    for (int c = 0; c < 50; ++c) acc += z1[g*50 + c] * w2[c*25 + j];
    z2[o] = fmaxf(acc, 0.f);
  }
  __syncthreads();
  if (tid < 64){
    float acc = b3[0];
    for (int c = 0; c < 25; ++c) acc += z2[tid*25 + c] * w3[c];
    out[tid] = acc;
  }
}

// ---------------------------------------------------------------- launcher
extern "C" void kernel_launch(void* const* d_in, const int* in_sizes, int n_in,
                              void* d_out, int out_size, void* d_ws, size_t ws_size,
                              hipStream_t stream){
  const float* x     = (const float*)d_in[0];
  const int*   ei    = (const int*)  d_in[1];
  const int*   batch = (const int*)  d_in[2];
  const float* plW   = (const float*)d_in[3];
  const float* plb   = (const float*)d_in[4];
  const float* preW  = (const float*)d_in[5];
  const float* preb  = (const float*)d_in[6];
  const float* postW = (const float*)d_in[7];
  const float* postb = (const float*)d_in[8];
  const float* linW  = (const float*)d_in[9];
  const float* linb  = (const float*)d_in[10];
  const float* bns   = (const float*)d_in[11];
  const float* bnb   = (const float*)d_in[12];
  const float* W1    = (const float*)d_in[13];
  const float* b1    = (const float*)d_in[14];
  const float* W2    = (const float*)d_in[15];
  const float* b2    = (const float*)d_in[16];
  const float* W3    = (const float*)d_in[17];
  const float* b3    = (const float*)d_in[18];
  float* out = (float*)d_out;

  // workspace layout (~76.4 MB)
  float* out2v = (float*)d_ws;                     // 750000
  float* zv    = out2v + 750000;                   // 750000
  float* baseb = zv + 750000;                      // NN*400 f32 = 16 MB
  unsigned short* W45S = (unsigned short*)(baseb + (size_t)NN*ROWP); // 614,400
  unsigned short* WgS  = W45S + (size_t)TOTW45;                      // 688,128
  float* pooled= (float*)(WgS + (size_t)TOTWG);                      // 4800
  float* bnS   = pooled + 4800;                    // 4*160
  unsigned short* out1b = (unsigned short*)(bnS + NL*160);  // NN*400
  unsigned short* aggb  = out1b + (size_t)NN*ROWP;          // NN*1600 = 32 MB
  // h0 aliases the TAIL of aggb: used only before the first k_gather write.
  float* h0 = (float*)(aggb + (size_t)NN*1600) - 750000;
  int* cnt = (int*)(aggb + (size_t)NN*1600);
  int* off = cnt + NN;
  int* cur = off + NN + 1;
  int* csr = cur + NN;

  k_init<<<(NN*NF + 255)/256, 256, 0, stream>>>(x, plW, plb, h0, cnt, bnS, pooled);
  k_count<<<(NE + 255)/256, 256, 0, stream>>>(ei, cnt);
  k_scan<<<1, 1024, 0, stream>>>(cnt, off, cur);
  k_scatter<<<(NE + 255)/256, 256, 0, stream>>>(ei, cur, csr);
  k_build<<<(TOTWG + 255)/256, 256, 0, stream>>>(preW, postW, W45S, WgS);

  const int NTILE = (NN + 31)/32;   // 313

  for (int l = 0; l < NL; ++l){
    const float* src = (l == 0) ? h0 : out2v;
    const float* bnSp = bnS + (l > 0 ? (l-1)*160 : 0);
    const float* sc = bns + (l > 0 ? (l-1)*75 : 0);
    const float* bb = bnb + (l > 0 ? (l-1)*75 : 0);
    k_gemm1<<<7*157, 256, 0, stream>>>(src, WgS, preb, bnSp, sc, bb, (l > 0),
                                       out1b, baseb, zv, l);
    k_gather<<<(NN*64)/256, 256, 0, stream>>>(out1b, baseb, off, csr, aggb);
    k_post<<<NT*NTILE, 128, 0, stream>>>(aggb, zv, off, W45S, postb, l);
    k_lin<<<157, 256, 0, stream>>>(zv, linW, linb, out2v, bnS + l*160, l);
  }

  k_bnpool<<<(NN*NF + 255)/256, 256, 0, stream>>>(out2v, bnS + 3*160,
                                                  bns + 3*75, bnb + 3*75, batch, pooled);
  k_head<<<1, 256, 0, stream>>>(pooled, W1, b1, W2, b2, W3, b3, out);
}